// Round 6
// baseline (219.331 us; speedup 1.0000x reference)
//
#include <hip/hip_runtime.h>
#include <hip/hip_bf16.h>

#define N_NODES 50000
#define N_EDGES 800000
#define DIM_IN  128
#define DIM_OUT 64
#define HEADS   4
#define NEG_SLOPE 0.2f
#define NPB 32                                    // nodes per gemm block
#define GEMM_BLOCKS ((N_NODES + NPB - 1) / NPB)   // 1563
#define N_PAD (GEMM_BLOCKS * NPB)                 // 50016
#define PAD 64                                    // padded CSR slots per node (Poisson(16): P(deg>64) ~ 1e-18; guarded)

// bf16 helpers (RNE pack, exact shift unpack)
__device__ __forceinline__ unsigned int f2bf(float f) {
    unsigned int u = __float_as_uint(f);
    return (u + 0x7FFFu + ((u >> 16) & 1u)) >> 16;
}
__device__ __forceinline__ float bf2f(unsigned int b) {
    return __uint_as_float(b << 16);
}
__device__ __forceinline__ float4 f4fma(float s, float4 w, float4 c) {
    c.x = fmaf(s, w.x, c.x); c.y = fmaf(s, w.y, c.y);
    c.z = fmaf(s, w.z, c.z); c.w = fmaf(s, w.w, c.w);
    return c;
}

// ---------------- Fat kernel: gemm-role blocks ∥ scatter-role blocks --------------
// role = blockIdx%3==0 -> gemm (VALU-bound), else -> scatter (latency-bound).
// h2 layout: [node][out 0..63][head 0..3] ushort  -> fused gather = 1 dwordx2/lane.
__global__ __launch_bounds__(256) void fat_kernel(
    const float* __restrict__ x, const float* __restrict__ W,
    const float* __restrict__ a,
    unsigned short* __restrict__ h2, float* __restrict__ s_i, float* __restrict__ s_j,
    const int* __restrict__ ei, int* __restrict__ cursor, unsigned short* __restrict__ sdst)
{
    __shared__ float4 xs[NPB][DIM_IN / 4];   // 16 KB (gemm role only)
    const int b = blockIdx.x;
    const int t = threadIdx.x;

    if (b % 3 != 0) {
        // ---------------- scatter role: padded-CSR bucket append (ushort) -------
        const int s = (b / 3) * 2 + (b % 3 - 1);          // 0..3125
        const int e = s * 256 + t;
        if (e < N_EDGES) {
            const int src = ei[e];
            const int r = atomicAdd(&cursor[src], 1);
            if (r < PAD) sdst[src * PAD + r] = (unsigned short)ei[N_EDGES + e];
        }
        return;
    }

    // ---------------- gemm role: h(bf16) = x @ W, s_i/s_j fp32 ------------------
    const int nb = (b / 3) * NPB;
    {
        const float4* xg = (const float4*)x;
        const int base = nb * (DIM_IN / 4);
        const int limit = N_NODES * (DIM_IN / 4);
#pragma unroll
        for (int r = 0; r < 4; ++r) {
            const int idx = t + 256 * r;
            const int g = base + idx;
            float4 v = {0.f, 0.f, 0.f, 0.f};
            if (g < limit) v = xg[g];
            ((float4*)&xs[0][0])[idx] = v;
        }
    }
    __syncthreads();

    const int nslot = t >> 6;
    const int head  = (t >> 4) & 3;
    const int oq    = t & 15;

    const float4* Wv = (const float4*)(W + head * (DIM_IN * DIM_OUT)) + oq;
    float4 acc[8];
#pragma unroll
    for (int k = 0; k < 8; ++k) acc[k] = make_float4(0.f, 0.f, 0.f, 0.f);

#pragma unroll 2
    for (int d4 = 0; d4 < DIM_IN / 4; ++d4) {
        const float4 w0 = Wv[(4 * d4 + 0) * 16];
        const float4 w1 = Wv[(4 * d4 + 1) * 16];
        const float4 w2 = Wv[(4 * d4 + 2) * 16];
        const float4 w3 = Wv[(4 * d4 + 3) * 16];
#pragma unroll
        for (int k = 0; k < 8; ++k) {
            const float4 xv = xs[nslot + 4 * k][d4];
            acc[k] = f4fma(xv.w, w3, f4fma(xv.z, w2, f4fma(xv.y, w1, f4fma(xv.x, w0, acc[k]))));
        }
    }

    const float4 ai = *(const float4*)(a + head * (2 * DIM_OUT) + oq * 4);
    const float4 aj = *(const float4*)(a + head * (2 * DIM_OUT) + DIM_OUT + oq * 4);
#pragma unroll
    for (int k = 0; k < 8; ++k) {
        const int n = nb + nslot + 4 * k;             // < N_PAD, buffers padded
        // transposed bf16 store: h2[n][o][head], o = oq*4+j
        unsigned short* hb = h2 + (size_t)n * (DIM_OUT * HEADS) + oq * 4 * HEADS + head;
        hb[0 * HEADS] = (unsigned short)f2bf(acc[k].x);
        hb[1 * HEADS] = (unsigned short)f2bf(acc[k].y);
        hb[2 * HEADS] = (unsigned short)f2bf(acc[k].z);
        hb[3 * HEADS] = (unsigned short)f2bf(acc[k].w);
        float pi = acc[k].x * ai.x + acc[k].y * ai.y + acc[k].z * ai.z + acc[k].w * ai.w;
        float pj = acc[k].x * aj.x + acc[k].y * aj.y + acc[k].z * aj.z + acc[k].w * aj.w;
#pragma unroll
        for (int off = 8; off > 0; off >>= 1) {
            pi += __shfl_down(pi, off, 16);
            pj += __shfl_down(pj, off, 16);
        }
        if (oq == 0) {
            s_i[n * HEADS + head] = pi;
            s_j[n * HEADS + head] = pj;
        }
    }
}

// ---------------- Fused per-src softmax + aggregate (one wave per node) -----------
__global__ __launch_bounds__(256) void fused_kernel(
    const int* __restrict__ cursor, const unsigned short* __restrict__ sdst,
    const float* __restrict__ s_i, const float* __restrict__ s_j,
    const unsigned short* __restrict__ h2, float* __restrict__ out)
{
    __shared__ float4 att_s[4][64];
    __shared__ int    dst_s[4][64];
    const int wid = (blockIdx.x * 256 + threadIdx.x) >> 6;   // node id
    const int w = (threadIdx.x >> 6) & 3;
    const int lane = threadIdx.x & 63;
    if (wid >= N_NODES) return;
    const int n = wid;
    const int d = min(cursor[n], PAD);
    const int start = n * PAD;

    float acc = 0.f;
    if (d > 0) {
        const float4 si = *(const float4*)(s_i + n * HEADS);
        float4 m4 = {-INFINITY, -INFINITY, -INFINITY, -INFINITY};
        float4 cz = {-INFINITY, -INFINITY, -INFINITY, -INFINITY};
        int cdst = 0;
        if (lane < d) {
            cdst = (int)sdst[start + lane];
            const float4 sj = *(const float4*)(s_j + cdst * HEADS);
            float z0 = si.x + sj.x, z1 = si.y + sj.y, z2 = si.z + sj.z, z3 = si.w + sj.w;
            cz.x = z0 >= 0.f ? z0 : NEG_SLOPE * z0;
            cz.y = z1 >= 0.f ? z1 : NEG_SLOPE * z1;
            cz.z = z2 >= 0.f ? z2 : NEG_SLOPE * z2;
            cz.w = z3 >= 0.f ? z3 : NEG_SLOPE * z3;
            m4 = cz;
        }
#pragma unroll
        for (int off = 32; off > 0; off >>= 1) {
            m4.x = fmaxf(m4.x, __shfl_xor(m4.x, off, 64));
            m4.y = fmaxf(m4.y, __shfl_xor(m4.y, off, 64));
            m4.z = fmaxf(m4.z, __shfl_xor(m4.z, off, 64));
            m4.w = fmaxf(m4.w, __shfl_xor(m4.w, off, 64));
        }
        float4 ex = {0.f, 0.f, 0.f, 0.f};
        if (lane < d) {
            ex.x = __expf(cz.x - m4.x);
            ex.y = __expf(cz.y - m4.y);
            ex.z = __expf(cz.z - m4.z);
            ex.w = __expf(cz.w - m4.w);
        }
        float4 sm = ex;
#pragma unroll
        for (int off = 32; off > 0; off >>= 1) {
            sm.x += __shfl_xor(sm.x, off, 64);
            sm.y += __shfl_xor(sm.y, off, 64);
            sm.z += __shfl_xor(sm.z, off, 64);
            sm.w += __shfl_xor(sm.w, off, 64);
        }
        if (lane < d) {
            att_s[w][lane] = make_float4(ex.x / sm.x, ex.y / sm.y, ex.z / sm.z, ex.w / sm.w);
            dst_s[w][lane] = cdst;
        }
        for (int e = 0; e < d; ++e) {
            const float4 a4 = att_s[w][e];      // wave-uniform LDS broadcast
            const int dd = dst_s[w][e];
            // one dwordx2 per lane = h[dd][o=lane][head 0..3] (4 bf16)
            const uint2 hv = *(const uint2*)(h2 + (size_t)dd * (DIM_OUT * HEADS) + lane * HEADS);
            acc += a4.x * bf2f(hv.x & 0xFFFFu) + a4.y * bf2f(hv.x >> 16)
                 + a4.z * bf2f(hv.y & 0xFFFFu) + a4.w * bf2f(hv.y >> 16);
        }
    }
    out[n * DIM_OUT + lane] = 0.25f * acc;
}

extern "C" void kernel_launch(void* const* d_in, const int* in_sizes, int n_in,
                              void* d_out, int out_size, void* d_ws, size_t ws_size,
                              hipStream_t stream) {
    const float* x  = (const float*)d_in[0];
    const int*   ei = (const int*)d_in[1];
    const float* W  = (const float*)d_in[2];
    const float* a  = (const float*)d_in[3];
    float* out = (float*)d_out;

    char* ws = (char*)d_ws;
    size_t off = 0;
    auto alloc = [&](size_t bytes) { void* p = ws + off; off = (off + bytes + 511) & ~size_t(511); return p; };
    unsigned short* h2 = (unsigned short*)alloc(sizeof(unsigned short) * N_PAD * DIM_OUT * HEADS); // 25.6 MB
    float* s_i    = (float*)alloc(sizeof(float) * N_PAD * HEADS);
    float* s_j    = (float*)alloc(sizeof(float) * N_PAD * HEADS);
    int*   cursor = (int*)alloc(sizeof(int) * N_NODES);
    unsigned short* sdst = (unsigned short*)alloc(sizeof(unsigned short) * N_NODES * PAD); // 6.4 MB

    hipMemsetAsync(cursor, 0, sizeof(int) * N_NODES, stream);

    // scatter (padded CSR append) co-scheduled with gemm: 1563 gemm + 3126 scatter
    fat_kernel<<<3 * GEMM_BLOCKS, 256, 0, stream>>>(x, W, a, h2, s_i, s_j, ei, cursor, sdst);

    // fused softmax + aggregate: one wave per node
    const int fb = (N_NODES * 64 + 255) / 256;
    fused_kernel<<<fb, 256, 0, stream>>>(cursor, sdst, s_i, s_j, h2, out);
}

// Round 7
// 203.031 us; speedup vs baseline: 1.0803x; 1.0803x over previous
//
#include <hip/hip_runtime.h>
#include <hip/hip_bf16.h>

#define N_NODES 50000
#define N_EDGES 800000
#define DIM_IN  128
#define DIM_OUT 64
#define HEADS   4
#define NEG_SLOPE 0.2f
#define NPB 32                                    // nodes per gemm block
#define GEMM_BLOCKS ((N_NODES + NPB - 1) / NPB)   // 1563
#define N_PAD (GEMM_BLOCKS * NPB)                 // 50016
#define PAD 64                                    // padded CSR slots per node (Poisson(16): P(deg>64) ~ 1e-18; guarded)

// bf16 helpers (RNE pack, exact shift unpack)
__device__ __forceinline__ unsigned int f2bf(float f) {
    unsigned int u = __float_as_uint(f);
    return (u + 0x7FFFu + ((u >> 16) & 1u)) >> 16;
}
__device__ __forceinline__ float bf2f(unsigned int b) {
    return __uint_as_float(b << 16);
}
__device__ __forceinline__ float4 f4fma(float s, float4 w, float4 c) {
    c.x = fmaf(s, w.x, c.x); c.y = fmaf(s, w.y, c.y);
    c.z = fmaf(s, w.z, c.z); c.w = fmaf(s, w.w, c.w);
    return c;
}

// ---------------- Fat kernel: gemm-role blocks ∥ scatter-role blocks --------------
// role = blockIdx%3==0 -> gemm (VALU-bound), else -> scatter (latency-bound).
// h2 layout: [node][out 0..63][head 0..3] ushort -> fused gather = 1 dwordx2/lane.
// Epilogue transposes through LDS (xs is dead after the K-loop) so global
// stores stay dense dwordx4 — R6's 2B scalar stores cost ~10 us in fat.
__global__ __launch_bounds__(256) void fat_kernel(
    const float* __restrict__ x, const float* __restrict__ W,
    const float* __restrict__ a,
    unsigned short* __restrict__ h2, float* __restrict__ s_i, float* __restrict__ s_j,
    const int* __restrict__ ei, int* __restrict__ cursor, unsigned short* __restrict__ sdst)
{
    __shared__ __align__(16) unsigned char smem[NPB * DIM_IN * 4];  // 16 KB, dual-use
    const int b = blockIdx.x;
    const int t = threadIdx.x;

    if (b % 3 != 0) {
        // ---------------- scatter role: padded-CSR bucket append (ushort) -------
        const int s = (b / 3) * 2 + (b % 3 - 1);          // 0..3125
        const int e = s * 256 + t;
        if (e < N_EDGES) {
            const int src = ei[e];
            const int r = atomicAdd(&cursor[src], 1);
            if (r < PAD) sdst[src * PAD + r] = (unsigned short)ei[N_EDGES + e];
        }
        return;
    }

    // ---------------- gemm role: h(bf16) = x @ W, s_i/s_j fp32 ------------------
    float4 (*xs)[DIM_IN / 4] = (float4 (*)[DIM_IN / 4])smem;
    const int nb = (b / 3) * NPB;
    {
        const float4* xg = (const float4*)x;
        const int base = nb * (DIM_IN / 4);
        const int limit = N_NODES * (DIM_IN / 4);
#pragma unroll
        for (int r = 0; r < 4; ++r) {
            const int idx = t + 256 * r;
            const int g = base + idx;
            float4 v = {0.f, 0.f, 0.f, 0.f};
            if (g < limit) v = xg[g];
            ((float4*)&xs[0][0])[idx] = v;
        }
    }
    __syncthreads();

    const int nslot = t >> 6;
    const int head  = (t >> 4) & 3;
    const int oq    = t & 15;

    const float4* Wv = (const float4*)(W + head * (DIM_IN * DIM_OUT)) + oq;
    float4 acc[8];
#pragma unroll
    for (int k = 0; k < 8; ++k) acc[k] = make_float4(0.f, 0.f, 0.f, 0.f);

#pragma unroll 2
    for (int d4 = 0; d4 < DIM_IN / 4; ++d4) {
        const float4 w0 = Wv[(4 * d4 + 0) * 16];
        const float4 w1 = Wv[(4 * d4 + 1) * 16];
        const float4 w2 = Wv[(4 * d4 + 2) * 16];
        const float4 w3 = Wv[(4 * d4 + 3) * 16];
#pragma unroll
        for (int k = 0; k < 8; ++k) {
            const float4 xv = xs[nslot + 4 * k][d4];
            acc[k] = f4fma(xv.w, w3, f4fma(xv.z, w2, f4fma(xv.y, w1, f4fma(xv.x, w0, acc[k]))));
        }
    }
    __syncthreads();   // xs consumed; smem becomes the transpose buffer

    // stage transposed bf16 tile in LDS: lt16[n_local*256 + o*4 + head]
    unsigned short* lt16 = (unsigned short*)smem;
#pragma unroll
    for (int k = 0; k < 8; ++k) {
        const int base = (nslot + 4 * k) * (DIM_OUT * HEADS) + oq * 16 + head;
        lt16[base + 0]  = (unsigned short)f2bf(acc[k].x);
        lt16[base + 4]  = (unsigned short)f2bf(acc[k].y);
        lt16[base + 8]  = (unsigned short)f2bf(acc[k].z);
        lt16[base + 12] = (unsigned short)f2bf(acc[k].w);
    }

    // scores while LDS writes drain (regs only)
    const float4 ai = *(const float4*)(a + head * (2 * DIM_OUT) + oq * 4);
    const float4 aj = *(const float4*)(a + head * (2 * DIM_OUT) + DIM_OUT + oq * 4);
#pragma unroll
    for (int k = 0; k < 8; ++k) {
        const int n = nb + nslot + 4 * k;             // < N_PAD, buffers padded
        float pi = acc[k].x * ai.x + acc[k].y * ai.y + acc[k].z * ai.z + acc[k].w * ai.w;
        float pj = acc[k].x * aj.x + acc[k].y * aj.y + acc[k].z * aj.z + acc[k].w * aj.w;
#pragma unroll
        for (int off = 8; off > 0; off >>= 1) {
            pi += __shfl_down(pi, off, 16);
            pj += __shfl_down(pj, off, 16);
        }
        if (oq == 0) {
            s_i[n * HEADS + head] = pi;
            s_j[n * HEADS + head] = pj;
        }
    }
    __syncthreads();

    // dense write-out: 1024 uint4 = 16 KB, coalesced dwordx4
    const uint4* lt4 = (const uint4*)smem;
    uint4* hg = (uint4*)(h2 + (size_t)nb * (DIM_OUT * HEADS));
#pragma unroll
    for (int r = 0; r < 4; ++r) {
        const int idx = t + 256 * r;
        hg[idx] = lt4[idx];
    }
}

// ---------------- Fused per-src softmax + aggregate (one wave per node) -----------
__global__ __launch_bounds__(256) void fused_kernel(
    const int* __restrict__ cursor, const unsigned short* __restrict__ sdst,
    const float* __restrict__ s_i, const float* __restrict__ s_j,
    const unsigned short* __restrict__ h2, float* __restrict__ out)
{
    __shared__ float4 att_s[4][64];
    __shared__ int    dst_s[4][64];
    const int wid = (blockIdx.x * 256 + threadIdx.x) >> 6;   // node id
    const int w = (threadIdx.x >> 6) & 3;
    const int lane = threadIdx.x & 63;
    if (wid >= N_NODES) return;
    const int n = wid;
    const int d = min(cursor[n], PAD);
    const int start = n * PAD;

    float acc = 0.f;
    if (d > 0) {
        const float4 si = *(const float4*)(s_i + n * HEADS);
        float4 m4 = {-INFINITY, -INFINITY, -INFINITY, -INFINITY};
        float4 cz = {-INFINITY, -INFINITY, -INFINITY, -INFINITY};
        int cdst = 0;
        if (lane < d) {
            cdst = (int)sdst[start + lane];
            const float4 sj = *(const float4*)(s_j + cdst * HEADS);
            float z0 = si.x + sj.x, z1 = si.y + sj.y, z2 = si.z + sj.z, z3 = si.w + sj.w;
            cz.x = z0 >= 0.f ? z0 : NEG_SLOPE * z0;
            cz.y = z1 >= 0.f ? z1 : NEG_SLOPE * z1;
            cz.z = z2 >= 0.f ? z2 : NEG_SLOPE * z2;
            cz.w = z3 >= 0.f ? z3 : NEG_SLOPE * z3;
            m4 = cz;
        }
#pragma unroll
        for (int off = 32; off > 0; off >>= 1) {
            m4.x = fmaxf(m4.x, __shfl_xor(m4.x, off, 64));
            m4.y = fmaxf(m4.y, __shfl_xor(m4.y, off, 64));
            m4.z = fmaxf(m4.z, __shfl_xor(m4.z, off, 64));
            m4.w = fmaxf(m4.w, __shfl_xor(m4.w, off, 64));
        }
        float4 ex = {0.f, 0.f, 0.f, 0.f};
        if (lane < d) {
            ex.x = __expf(cz.x - m4.x);
            ex.y = __expf(cz.y - m4.y);
            ex.z = __expf(cz.z - m4.z);
            ex.w = __expf(cz.w - m4.w);
        }
        float4 sm = ex;
#pragma unroll
        for (int off = 32; off > 0; off >>= 1) {
            sm.x += __shfl_xor(sm.x, off, 64);
            sm.y += __shfl_xor(sm.y, off, 64);
            sm.z += __shfl_xor(sm.z, off, 64);
            sm.w += __shfl_xor(sm.w, off, 64);
        }
        if (lane < d) {
            att_s[w][lane] = make_float4(ex.x / sm.x, ex.y / sm.y, ex.z / sm.z, ex.w / sm.w);
            dst_s[w][lane] = cdst;
        }
        for (int e = 0; e < d; ++e) {
            const float4 a4 = att_s[w][e];      // wave-uniform LDS broadcast
            const int dd = dst_s[w][e];
            // one dwordx2 per lane = h[dd][o=lane][head 0..3] (4 bf16)
            const uint2 hv = *(const uint2*)(h2 + (size_t)dd * (DIM_OUT * HEADS) + lane * HEADS);
            acc += a4.x * bf2f(hv.x & 0xFFFFu) + a4.y * bf2f(hv.x >> 16)
                 + a4.z * bf2f(hv.y & 0xFFFFu) + a4.w * bf2f(hv.y >> 16);
        }
    }
    out[n * DIM_OUT + lane] = 0.25f * acc;
}

extern "C" void kernel_launch(void* const* d_in, const int* in_sizes, int n_in,
                              void* d_out, int out_size, void* d_ws, size_t ws_size,
                              hipStream_t stream) {
    const float* x  = (const float*)d_in[0];
    const int*   ei = (const int*)d_in[1];
    const float* W  = (const float*)d_in[2];
    const float* a  = (const float*)d_in[3];
    float* out = (float*)d_out;

    char* ws = (char*)d_ws;
    size_t off = 0;
    auto alloc = [&](size_t bytes) { void* p = ws + off; off = (off + bytes + 511) & ~size_t(511); return p; };
    unsigned short* h2 = (unsigned short*)alloc(sizeof(unsigned short) * N_PAD * DIM_OUT * HEADS); // 25.6 MB
    float* s_i    = (float*)alloc(sizeof(float) * N_PAD * HEADS);
    float* s_j    = (float*)alloc(sizeof(float) * N_PAD * HEADS);
    int*   cursor = (int*)alloc(sizeof(int) * N_NODES);
    unsigned short* sdst = (unsigned short*)alloc(sizeof(unsigned short) * N_NODES * PAD); // 6.4 MB

    hipMemsetAsync(cursor, 0, sizeof(int) * N_NODES, stream);

    // scatter (padded CSR append) co-scheduled with gemm: 1563 gemm + 3126 scatter
    fat_kernel<<<3 * GEMM_BLOCKS, 256, 0, stream>>>(x, W, a, h2, s_i, s_j, ei, cursor, sdst);

    // fused softmax + aggregate: one wave per node
    const int fb = (N_NODES * 64 + 255) / 256;
    fused_kernel<<<fb, 256, 0, stream>>>(cursor, sdst, s_i, s_j, h2, out);
}

// Round 8
// 202.082 us; speedup vs baseline: 1.0854x; 1.0047x over previous
//
#include <hip/hip_runtime.h>
#include <hip/hip_bf16.h>

#define N_NODES 50000
#define N_EDGES 800000
#define DIM_IN  128
#define DIM_OUT 64
#define HEADS   4
#define NEG_SLOPE 0.2f
#define NPB 32                                    // nodes per gemm block
#define GEMM_BLOCKS ((N_NODES + NPB - 1) / NPB)   // 1563
#define N_PAD (GEMM_BLOCKS * NPB)                 // 50016
#define PAD 64                                    // padded CSR slots per node (Poisson(16); guarded)
#define SCAT4_THREADS (N_EDGES / 4)               // 200000 threads, 4 edges each
#define SCAT4_BLOCKS ((SCAT4_THREADS + 255) / 256) // 782
#define FAT_GRID (3 * SCAT4_BLOCKS)               // 2346: pattern (gemm,gemm,scatter)

// bf16 helpers (RNE pack, exact shift unpack)
__device__ __forceinline__ unsigned int f2bf(float f) {
    unsigned int u = __float_as_uint(f);
    return (u + 0x7FFFu + ((u >> 16) & 1u)) >> 16;
}
__device__ __forceinline__ float bf2f(unsigned int b) {
    return __uint_as_float(b << 16);
}
__device__ __forceinline__ float4 f4fma(float s, float4 w, float4 c) {
    c.x = fmaf(s, w.x, c.x); c.y = fmaf(s, w.y, c.y);
    c.z = fmaf(s, w.z, c.z); c.w = fmaf(s, w.w, c.w);
    return c;
}

// ---------------- Fat kernel: gemm-role blocks ∥ scatter-role blocks --------------
// b%3==2 -> scatter (latency-bound, int4 edge reads, 4 atomics in flight);
// else -> gemm (VALU-bound). 2:1 mix keeps every CU issuing FMAs while
// scatter waves wait on atomics (m114 overlap).
__global__ __launch_bounds__(256) void fat_kernel(
    const float* __restrict__ x, const float* __restrict__ W,
    const float* __restrict__ a,
    unsigned short* __restrict__ h2, float* __restrict__ s_i, float* __restrict__ s_j,
    const int* __restrict__ ei, int* __restrict__ cursor, unsigned short* __restrict__ sdst)
{
    __shared__ __align__(16) unsigned char smem[NPB * DIM_IN * 4];  // 16 KB, dual-use
    const int b = blockIdx.x;
    const int t = threadIdx.x;

    if (b % 3 == 2) {
        // ---------------- scatter role: padded-CSR append, 4 edges/thread -------
        const int i = (b / 3) * 256 + t;                 // 0..200191
        if (i < SCAT4_THREADS) {
            const int e4 = i * 4;
            const int4 srcs = *(const int4*)(ei + e4);
            const int4 dsts = *(const int4*)(ei + N_EDGES + e4);
            const int r0 = atomicAdd(&cursor[srcs.x], 1);
            const int r1 = atomicAdd(&cursor[srcs.y], 1);
            const int r2 = atomicAdd(&cursor[srcs.z], 1);
            const int r3 = atomicAdd(&cursor[srcs.w], 1);
            if (r0 < PAD) sdst[srcs.x * PAD + r0] = (unsigned short)dsts.x;
            if (r1 < PAD) sdst[srcs.y * PAD + r1] = (unsigned short)dsts.y;
            if (r2 < PAD) sdst[srcs.z * PAD + r2] = (unsigned short)dsts.z;
            if (r3 < PAD) sdst[srcs.w * PAD + r3] = (unsigned short)dsts.w;
        }
        return;
    }

    // ---------------- gemm role: h(bf16) = x @ W, s_i/s_j fp32 ------------------
    const int g = (b / 3) * 2 + (b % 3);                 // 0..1563
    if (g >= GEMM_BLOCKS) return;
    float4 (*xs)[DIM_IN / 4] = (float4 (*)[DIM_IN / 4])smem;
    const int nb = g * NPB;
    {
        const float4* xg = (const float4*)x;
        const int base = nb * (DIM_IN / 4);
        const int limit = N_NODES * (DIM_IN / 4);
#pragma unroll
        for (int r = 0; r < 4; ++r) {
            const int idx = t + 256 * r;
            const int gi = base + idx;
            float4 v = {0.f, 0.f, 0.f, 0.f};
            if (gi < limit) v = xg[gi];
            ((float4*)&xs[0][0])[idx] = v;
        }
    }
    __syncthreads();

    const int nslot = t >> 6;
    const int head  = (t >> 4) & 3;
    const int oq    = t & 15;

    const float4* Wv = (const float4*)(W + head * (DIM_IN * DIM_OUT)) + oq;
    float4 acc[8];
#pragma unroll
    for (int k = 0; k < 8; ++k) acc[k] = make_float4(0.f, 0.f, 0.f, 0.f);

#pragma unroll 2
    for (int d4 = 0; d4 < DIM_IN / 4; ++d4) {
        const float4 w0 = Wv[(4 * d4 + 0) * 16];
        const float4 w1 = Wv[(4 * d4 + 1) * 16];
        const float4 w2 = Wv[(4 * d4 + 2) * 16];
        const float4 w3 = Wv[(4 * d4 + 3) * 16];
#pragma unroll
        for (int k = 0; k < 8; ++k) {
            const float4 xv = xs[nslot + 4 * k][d4];
            acc[k] = f4fma(xv.w, w3, f4fma(xv.z, w2, f4fma(xv.y, w1, f4fma(xv.x, w0, acc[k]))));
        }
    }
    __syncthreads();   // xs consumed; smem becomes the transpose buffer

    // stage transposed bf16 tile in LDS: lt16[n_local*256 + o*4 + head]
    unsigned short* lt16 = (unsigned short*)smem;
#pragma unroll
    for (int k = 0; k < 8; ++k) {
        const int base = (nslot + 4 * k) * (DIM_OUT * HEADS) + oq * 16 + head;
        lt16[base + 0]  = (unsigned short)f2bf(acc[k].x);
        lt16[base + 4]  = (unsigned short)f2bf(acc[k].y);
        lt16[base + 8]  = (unsigned short)f2bf(acc[k].z);
        lt16[base + 12] = (unsigned short)f2bf(acc[k].w);
    }

    // scores while LDS writes drain (regs only)
    const float4 ai = *(const float4*)(a + head * (2 * DIM_OUT) + oq * 4);
    const float4 aj = *(const float4*)(a + head * (2 * DIM_OUT) + DIM_OUT + oq * 4);
#pragma unroll
    for (int k = 0; k < 8; ++k) {
        const int n = nb + nslot + 4 * k;             // < N_PAD, buffers padded
        float pi = acc[k].x * ai.x + acc[k].y * ai.y + acc[k].z * ai.z + acc[k].w * ai.w;
        float pj = acc[k].x * aj.x + acc[k].y * aj.y + acc[k].z * aj.z + acc[k].w * aj.w;
#pragma unroll
        for (int off = 8; off > 0; off >>= 1) {
            pi += __shfl_down(pi, off, 16);
            pj += __shfl_down(pj, off, 16);
        }
        if (oq == 0) {
            s_i[n * HEADS + head] = pi;
            s_j[n * HEADS + head] = pj;
        }
    }
    __syncthreads();

    // dense write-out: 1024 uint4 = 16 KB, coalesced dwordx4
    const uint4* lt4 = (const uint4*)smem;
    uint4* hg = (uint4*)(h2 + (size_t)nb * (DIM_OUT * HEADS));
#pragma unroll
    for (int r = 0; r < 4; ++r) {
        const int idx = t + 256 * r;
        hg[idx] = lt4[idx];
    }
}

// ---------------- Fused per-src softmax + aggregate (one wave per node) -----------
// Aggregate loop unrolled x4: 4 independent uint2 gathers in flight per wave.
__global__ __launch_bounds__(256) void fused_kernel(
    const int* __restrict__ cursor, const unsigned short* __restrict__ sdst,
    const float* __restrict__ s_i, const float* __restrict__ s_j,
    const unsigned short* __restrict__ h2, float* __restrict__ out)
{
    __shared__ float4 att_s[4][64];
    __shared__ int    dst_s[4][64];
    const int wid = (blockIdx.x * 256 + threadIdx.x) >> 6;   // node id
    const int w = (threadIdx.x >> 6) & 3;
    const int lane = threadIdx.x & 63;
    if (wid >= N_NODES) return;
    const int n = wid;
    const int d = min(cursor[n], PAD);
    const int start = n * PAD;

    float acc = 0.f;
    if (d > 0) {
        const float4 si = *(const float4*)(s_i + n * HEADS);
        float4 m4 = {-INFINITY, -INFINITY, -INFINITY, -INFINITY};
        float4 cz = {-INFINITY, -INFINITY, -INFINITY, -INFINITY};
        int cdst = 0;
        if (lane < d) {
            cdst = (int)sdst[start + lane];
            const float4 sj = *(const float4*)(s_j + cdst * HEADS);
            float z0 = si.x + sj.x, z1 = si.y + sj.y, z2 = si.z + sj.z, z3 = si.w + sj.w;
            cz.x = z0 >= 0.f ? z0 : NEG_SLOPE * z0;
            cz.y = z1 >= 0.f ? z1 : NEG_SLOPE * z1;
            cz.z = z2 >= 0.f ? z2 : NEG_SLOPE * z2;
            cz.w = z3 >= 0.f ? z3 : NEG_SLOPE * z3;
            m4 = cz;
        }
#pragma unroll
        for (int off = 32; off > 0; off >>= 1) {
            m4.x = fmaxf(m4.x, __shfl_xor(m4.x, off, 64));
            m4.y = fmaxf(m4.y, __shfl_xor(m4.y, off, 64));
            m4.z = fmaxf(m4.z, __shfl_xor(m4.z, off, 64));
            m4.w = fmaxf(m4.w, __shfl_xor(m4.w, off, 64));
        }
        float4 ex = {0.f, 0.f, 0.f, 0.f};
        if (lane < d) {
            ex.x = __expf(cz.x - m4.x);
            ex.y = __expf(cz.y - m4.y);
            ex.z = __expf(cz.z - m4.z);
            ex.w = __expf(cz.w - m4.w);
        }
        float4 sm = ex;
#pragma unroll
        for (int off = 32; off > 0; off >>= 1) {
            sm.x += __shfl_xor(sm.x, off, 64);
            sm.y += __shfl_xor(sm.y, off, 64);
            sm.z += __shfl_xor(sm.z, off, 64);
            sm.w += __shfl_xor(sm.w, off, 64);
        }
        if (lane < d) {
            att_s[w][lane] = make_float4(ex.x / sm.x, ex.y / sm.y, ex.z / sm.z, ex.w / sm.w);
            dst_s[w][lane] = cdst;
        }

        const unsigned short* hbase = h2 + lane * HEADS;
        int e = 0;
        for (; e + 4 <= d; e += 4) {
            const int d0 = dst_s[w][e + 0];
            const int d1 = dst_s[w][e + 1];
            const int d2 = dst_s[w][e + 2];
            const int d3 = dst_s[w][e + 3];
            // 4 independent gathers issued back-to-back
            const uint2 h0 = *(const uint2*)(hbase + (size_t)d0 * (DIM_OUT * HEADS));
            const uint2 h1 = *(const uint2*)(hbase + (size_t)d1 * (DIM_OUT * HEADS));
            const uint2 h2v = *(const uint2*)(hbase + (size_t)d2 * (DIM_OUT * HEADS));
            const uint2 h3 = *(const uint2*)(hbase + (size_t)d3 * (DIM_OUT * HEADS));
            const float4 a0 = att_s[w][e + 0];
            const float4 a1 = att_s[w][e + 1];
            const float4 a2 = att_s[w][e + 2];
            const float4 a3 = att_s[w][e + 3];
            acc += a0.x * bf2f(h0.x & 0xFFFFu) + a0.y * bf2f(h0.x >> 16)
                 + a0.z * bf2f(h0.y & 0xFFFFu) + a0.w * bf2f(h0.y >> 16);
            acc += a1.x * bf2f(h1.x & 0xFFFFu) + a1.y * bf2f(h1.x >> 16)
                 + a1.z * bf2f(h1.y & 0xFFFFu) + a1.w * bf2f(h1.y >> 16);
            acc += a2.x * bf2f(h2v.x & 0xFFFFu) + a2.y * bf2f(h2v.x >> 16)
                 + a2.z * bf2f(h2v.y & 0xFFFFu) + a2.w * bf2f(h2v.y >> 16);
            acc += a3.x * bf2f(h3.x & 0xFFFFu) + a3.y * bf2f(h3.x >> 16)
                 + a3.z * bf2f(h3.y & 0xFFFFu) + a3.w * bf2f(h3.y >> 16);
        }
        for (; e < d; ++e) {
            const int dd = dst_s[w][e];
            const float4 a4 = att_s[w][e];
            const uint2 hv = *(const uint2*)(hbase + (size_t)dd * (DIM_OUT * HEADS));
            acc += a4.x * bf2f(hv.x & 0xFFFFu) + a4.y * bf2f(hv.x >> 16)
                 + a4.z * bf2f(hv.y & 0xFFFFu) + a4.w * bf2f(hv.y >> 16);
        }
    }
    out[n * DIM_OUT + lane] = 0.25f * acc;
}

extern "C" void kernel_launch(void* const* d_in, const int* in_sizes, int n_in,
                              void* d_out, int out_size, void* d_ws, size_t ws_size,
                              hipStream_t stream) {
    const float* x  = (const float*)d_in[0];
    const int*   ei = (const int*)d_in[1];
    const float* W  = (const float*)d_in[2];
    const float* a  = (const float*)d_in[3];
    float* out = (float*)d_out;

    char* ws = (char*)d_ws;
    size_t off = 0;
    auto alloc = [&](size_t bytes) { void* p = ws + off; off = (off + bytes + 511) & ~size_t(511); return p; };
    unsigned short* h2 = (unsigned short*)alloc(sizeof(unsigned short) * N_PAD * DIM_OUT * HEADS); // 25.6 MB
    float* s_i    = (float*)alloc(sizeof(float) * N_PAD * HEADS);
    float* s_j    = (float*)alloc(sizeof(float) * N_PAD * HEADS);
    int*   cursor = (int*)alloc(sizeof(int) * N_NODES);
    unsigned short* sdst = (unsigned short*)alloc(sizeof(unsigned short) * N_NODES * PAD); // 6.4 MB

    hipMemsetAsync(cursor, 0, sizeof(int) * N_NODES, stream);

    // scatter (padded CSR append) co-scheduled with gemm: 1563 gemm + 782 scatter
    fat_kernel<<<FAT_GRID, 256, 0, stream>>>(x, W, a, h2, s_i, s_j, ei, cursor, sdst);

    // fused softmax + aggregate: one wave per node
    const int fb = (N_NODES * 64 + 255) / 256;
    fused_kernel<<<fb, 256, 0, stream>>>(cursor, sdst, s_i, s_j, h2, out);
}